// Round 16
// baseline (268.179 us; speedup 1.0000x reference)
//
#include <hip/hip_runtime.h>
#include <math.h>

#define PIX 4096
#define O_CH 512
#define CV_PITCH 68   // f32 words per phi row in LDS (64 data + 4 pad)
#define NY_PITCH 36   // u32 (bf16x2) per ny row

// bf16 weight-plane offsets (ushorts): g[512x256], x[512x512], c[512x256]
#define WOFF_G 0
#define WOFF_X 131072
#define WOFF_C 393216
#define W_ELEMS 524288

typedef __attribute__((ext_vector_type(8))) short s16x8;
typedef __attribute__((ext_vector_type(4))) float f32x4;
typedef __attribute__((ext_vector_type(2))) float f32x2;

__device__ __forceinline__ unsigned cvt_pk_bf16(float a, float b) {
  unsigned r;
  asm("v_cvt_pk_bf16_f32 %0, %1, %2" : "=v"(r) : "v"(a), "v"(b));
  return r;
}

// ---------------- weight pre-conversion: f32 -> bf16 hi/lo planes ----------------
__global__ __launch_bounds__(256) void conv_w(
    const float* __restrict__ gw, const float* __restrict__ xw,
    const float* __restrict__ cw,
    ushort* __restrict__ WH, ushort* __restrict__ WL)
{
  const int r = blockIdx.y;
  const float* src = (r == 0) ? gw : ((r == 1) ? xw : cw);
  const int n4 = (r == 1) ? 65536 : 32768;   // float4 count
  const int doff = (r == 0) ? WOFF_G : ((r == 1) ? WOFF_X : WOFF_C);
  const int i = blockIdx.x * 256 + threadIdx.x;
  if (i >= n4) return;
  float4 v = ((const float4*)src)[i];
  unsigned h01 = cvt_pk_bf16(v.x, v.y);
  unsigned h23 = cvt_pk_bf16(v.z, v.w);
  float l0 = v.x - __uint_as_float(h01 << 16);
  float l1 = v.y - __uint_as_float(h01 & 0xffff0000u);
  float l2 = v.z - __uint_as_float(h23 << 16);
  float l3 = v.w - __uint_as_float(h23 & 0xffff0000u);
  unsigned lo01 = cvt_pk_bf16(l0, l1);
  unsigned lo23 = cvt_pk_bf16(l2, l3);
  ((uint2*)(WH + doff))[i] = make_uint2(h01, h23);
  ((uint2*)(WL + doff))[i] = make_uint2(lo01, lo23);
}

// ---------------- merged MFMA GEMM (split-bf16), 512-thread / 8-wave blocks ----
// bz<8: z[b] = relu(g_w*g[b]) + x_w*x[b];  bz>=8: phi0[b] = c_w*contour[b]
__global__ __launch_bounds__(512, 4) void mfma_gemm_all(
    const float* __restrict__ g, const float* __restrict__ x,
    const float* __restrict__ contour,
    const ushort* __restrict__ WHg, const ushort* __restrict__ WLg,
    float* __restrict__ z, float* __restrict__ phi0)
{
  __shared__ ushort WHs[8192], WLs[8192], AHs[8192], ALs[8192];  // 64 KB
  const int t = threadIdx.x;
  const int lane = t & 63, wave = t >> 6;   // 8 waves
  const int wm = wave & 1, wn = wave >> 1;  // 2 x 4 wave grid
  const int rowA = lane & 15, kg = lane >> 4;
  const int aph = wave & 1;                 // A-stage: p-half this wave covers
  const int akg = wave >> 1;                // A-stage: k-subgroup 0..3
  const int pb = blockIdx.x * 128, ob = blockIdx.y * 128;
  const int bz = blockIdx.z;
  const bool isZ = bz < 8;
  const int b = isZ ? bz : bz - 8;

  const int woff1 = isZ ? WOFF_G : WOFF_C;
  const float* A1 = (isZ ? g : contour) + (size_t)b * 256 * PIX;
  const float* A2 = x + (size_t)(isZ ? b : 0) * 512 * PIX;  // used only when isZ
  float* out = (isZ ? z : phi0) + (size_t)b * O_CH * PIX;
  const int nsteps = isZ ? 12 : 4;

  f32x4 acc[4][2];
#pragma unroll
  for (int mi = 0; mi < 4; ++mi)
#pragma unroll
    for (int ni = 0; ni < 2; ++ni) acc[mi][ni] = (f32x4){0.f, 0.f, 0.f, 0.f};

  float pf[2][8];   // prefetched A values for the CURRENT step: [ch][j]

  {
    const float* acp = A1 + pb + aph * 64 + lane;
#pragma unroll
    for (int ch = 0; ch < 2; ++ch)
#pragma unroll
      for (int j = 0; j < 8; ++j)
        pf[ch][j] = acp[(size_t)(ch * 32 + akg * 8 + j) * PIX];
  }

  for (int st = 0; st < nsteps; ++st) {
    const bool s2 = st >= 4;
    const int K = s2 ? 512 : 256;
    const int woff = s2 ? WOFF_X : woff1;
    const int kb = (s2 ? st - 4 : st) * 64;

    {
      const int o_r = t >> 2, hq = t & 3;   // 4 threads per o-row, 16 k each
      const size_t wbase = (size_t)woff + (size_t)(ob + o_r) * K + kb + hq * 16;
      const ushort* whrow = WHg + wbase;
      const ushort* wlrow = WLg + wbase;
#pragma unroll
      for (int i = 0; i < 2; ++i) {
        int j = 2 * hq + i;
        int idx = o_r * 64 + ((j ^ (o_r & 7)) << 3);
        *(s16x8*)&WHs[idx] = *(const s16x8*)(whrow + i * 8);
        *(s16x8*)&WLs[idx] = *(const s16x8*)(wlrow + i * 8);
      }
    }
    {
      const int rp = aph * 64 + lane;
#pragma unroll
      for (int ch = 0; ch < 2; ++ch) {
        unsigned h[4], l[4];
#pragma unroll
        for (int j2 = 0; j2 < 4; ++j2) {
          float v0 = pf[ch][2 * j2], v1 = pf[ch][2 * j2 + 1];
          h[j2] = cvt_pk_bf16(v0, v1);
          float lo0 = v0 - __uint_as_float(h[j2] << 16);
          float lo1 = v1 - __uint_as_float(h[j2] & 0xffff0000u);
          l[j2] = cvt_pk_bf16(lo0, lo1);
        }
        int grp = ch * 4 + akg;
        int idx = rp * 64 + ((grp ^ (rp & 7)) << 3);
        *(uint4*)&AHs[idx] = make_uint4(h[0], h[1], h[2], h[3]);
        *(uint4*)&ALs[idx] = make_uint4(l[0], l[1], l[2], l[3]);
      }
    }
    __syncthreads();

    if (st + 1 < nsteps) {
      const bool n2 = (st + 1) >= 4;
      const float* Ab = n2 ? A2 : A1;
      const int kbn = (n2 ? st + 1 - 4 : st + 1) * 64;
      const float* acp = Ab + (size_t)kbn * PIX + pb + aph * 64 + lane;
#pragma unroll
      for (int ch = 0; ch < 2; ++ch)
#pragma unroll
        for (int j = 0; j < 8; ++j)
          pf[ch][j] = acp[(size_t)(ch * 32 + akg * 8 + j) * PIX];
    }

#pragma unroll
    for (int ks = 0; ks < 2; ++ks) {
      s16x8 wh[4], wlv[4], ah[2], alv[2];
#pragma unroll
      for (int mi = 0; mi < 4; ++mi) {
        int row = wm * 64 + mi * 16 + rowA;
        int idx = row * 64 + (((ks * 4 + kg) ^ (row & 7)) << 3);
        wh[mi]  = *(const s16x8*)&WHs[idx];
        wlv[mi] = *(const s16x8*)&WLs[idx];
      }
#pragma unroll
      for (int ni = 0; ni < 2; ++ni) {
        int row = wn * 32 + ni * 16 + rowA;
        int idx = row * 64 + (((ks * 4 + kg) ^ (row & 7)) << 3);
        ah[ni]  = *(const s16x8*)&AHs[idx];
        alv[ni] = *(const s16x8*)&ALs[idx];
      }
#pragma unroll
      for (int mi = 0; mi < 4; ++mi)
#pragma unroll
        for (int ni = 0; ni < 2; ++ni) {
          acc[mi][ni] = __builtin_amdgcn_mfma_f32_16x16x32_bf16(wh[mi],  ah[ni],  acc[mi][ni], 0, 0, 0);
          acc[mi][ni] = __builtin_amdgcn_mfma_f32_16x16x32_bf16(wh[mi],  alv[ni], acc[mi][ni], 0, 0, 0);
          acc[mi][ni] = __builtin_amdgcn_mfma_f32_16x16x32_bf16(wlv[mi], ah[ni],  acc[mi][ni], 0, 0, 0);
        }
    }
    if (isZ && st == 3) {
#pragma unroll
      for (int mi = 0; mi < 4; ++mi)
#pragma unroll
        for (int ni = 0; ni < 2; ++ni)
#pragma unroll
          for (int r = 0; r < 4; ++r) acc[mi][ni][r] = fmaxf(acc[mi][ni][r], 0.f);
    }
    __syncthreads();
  }

  const int orow = (lane >> 4) * 4, pcol = lane & 15;
#pragma unroll
  for (int mi = 0; mi < 4; ++mi)
#pragma unroll
    for (int ni = 0; ni < 2; ++ni)
#pragma unroll
      for (int r = 0; r < 4; ++r)
        out[(size_t)(ob + wm * 64 + mi * 16 + orow + r) * PIX +
            pb + wn * 32 + ni * 16 + pcol] = acc[mi][ni][r];
}

// ---------------- Chan-Vese: 2 planes per block (barrier amortization + ILP) ----
__device__ __forceinline__ float fast_atan(float x) {
  float a = __builtin_fabsf(x);
  float inv = __builtin_amdgcn_rcpf(a);
  bool big = a > 1.f;
  float tt = big ? inv : a;
  float t2 = tt * tt;
  float p = fmaf(t2, 0.0208351f, -0.0851330f);
  p = fmaf(t2, p, 0.1801410f);
  p = fmaf(t2, p, -0.3302995f);
  p = fmaf(t2, p, 0.9998660f);
  p = p * tt;
  float r = big ? (1.57079632679f - p) : p;
  return __builtin_copysignf(r, x);
}

// Two planes per block: pass1(A);pass1(B);bar;pass2(A);pass2(B);bar — halves
// barrier rate and lets the compiler interleave the two independent streams
// (fills rsq/rcp latency). ny bf16 (time-neutral per r8/r14) keeps LDS at
// 53.3 KB -> 3 blocks/CU. (256,2): VGPR cap 256 so spill is impossible (r4).
__global__ __launch_bounds__(256, 2) void chanvese(
    const float* __restrict__ zb, float* __restrict__ ob,
    const float* __restrict__ dtp, const float* __restrict__ lamp)
{
  __shared__ float phi_l[2][64 * CV_PITCH];     // 2 x 17408 B
  __shared__ unsigned ny_l[2][64 * NY_PITCH];   // 2 x 9216 B
  __shared__ float red[24];
  const int t = threadIdx.x;
  const int lane = t & 63, wv = t >> 6;
  const int row = t >> 2, s = t & 3;
  const size_t gb0 = (size_t)blockIdx.x * PIX + row * 64 + s * 16;
  const size_t gb1 = gb0 + (size_t)2048 * PIX;
  const float dtv = dtp[0], lam = lamp[0];
  const float INV_PI = 0.31830988618379067f;
  const float dtpi = dtv * INV_PI;
  const float fy = (row == 0 || row == 63) ? 1.f : 0.5f;
  const float exl = (s == 0) ? 2.f : 1.f;
  const float exr = (s == 3) ? 2.f : 1.f;
  const int my = row * CV_PITCH + s * 16;
  const int ub = ((row == 0) ? 0 : row - 1) * CV_PITCH + s * 16;
  const int db = ((row == 63) ? 63 : row + 1) * CV_PITCH + s * 16;
  const int myn = row * NY_PITCH + s * 8;
  const int ubn = ((row == 0) ? 0 : row - 1) * NY_PITCH + s * 8;
  const int dbn = ((row == 63) ? 63 : row + 1) * NY_PITCH + s * 8;
  const f32x2 eps2 = {1e-8f, 1e-8f};

  f32x2 I2[2][8], ph2[2][8], nx2[2][8];
  float S_at[2], S_iat[2], sumI[2];
  {
    float sI[2], sa[2], si[2];
#pragma unroll
    for (int pl = 0; pl < 2; ++pl) {
      const size_t gb = pl ? gb1 : gb0;
      sI[pl] = 0.f; sa[pl] = 0.f; si[pl] = 0.f;
#pragma unroll
      for (int q = 0; q < 4; ++q) {
        f32x4 iv = *(const f32x4*)(zb + gb + q * 4);
        f32x4 pv = *(const f32x4*)(ob + gb + q * 4);
        I2[pl][2 * q]     = (f32x2){iv[0], iv[1]};
        I2[pl][2 * q + 1] = (f32x2){iv[2], iv[3]};
        ph2[pl][2 * q]     = (f32x2){pv[0], pv[1]};
        ph2[pl][2 * q + 1] = (f32x2){pv[2], pv[3]};
        *(f32x4*)&phi_l[pl][my + q * 4] = pv;
      }
#pragma unroll
      for (int p = 0; p < 8; ++p) {
        sI[pl] += I2[pl][p].x + I2[pl][p].y;
        float a0 = fast_atan(ph2[pl][p].x), a1 = fast_atan(ph2[pl][p].y);
        sa[pl] += a0 + a1;
        si[pl] = fmaf(I2[pl][p].x, a0, fmaf(I2[pl][p].y, a1, si[pl]));
      }
    }
#pragma unroll
    for (int off = 32; off; off >>= 1)
#pragma unroll
      for (int pl = 0; pl < 2; ++pl) {
        sI[pl] += __shfl_xor(sI[pl], off);
        sa[pl] += __shfl_xor(sa[pl], off);
        si[pl] += __shfl_xor(si[pl], off);
      }
    if (lane == 0)
#pragma unroll
      for (int pl = 0; pl < 2; ++pl) {
        red[pl * 12 + wv] = sa[pl];
        red[pl * 12 + 4 + wv] = si[pl];
        red[pl * 12 + 8 + wv] = sI[pl];
      }
    __syncthreads();
#pragma unroll
    for (int pl = 0; pl < 2; ++pl) {
      S_at[pl]  = red[pl*12+0] + red[pl*12+1] + red[pl*12+2] + red[pl*12+3];
      S_iat[pl] = red[pl*12+4] + red[pl*12+5] + red[pl*12+6] + red[pl*12+7];
      sumI[pl]  = red[pl*12+8] + red[pl*12+9] + red[pl*12+10] + red[pl*12+11];
    }
    __syncthreads();  // protect red before first in-loop write
  }

  for (int it = 0; it < 10; ++it) {
    float lam12[2], ms12[2];
#pragma unroll
    for (int pl = 0; pl < 2; ++pl) {
      float a1 = fmaf(INV_PI, S_at[pl], 2048.f);
      float sIH = fmaf(INV_PI, S_iat[pl], 0.5f * sumI[pl]);
      float c1 = sIH * __builtin_amdgcn_rcpf(a1 + 1e-8f);
      float c2 = (sumI[pl] - sIH) * __builtin_amdgcn_rcpf(4096.f - a1 + 1e-8f);
      lam12[pl] = lam * (c1 - c2);
      ms12[pl] = -(c1 + c2);
    }

    // ---- pass 1 (both planes): normals; nx in regs, ny -> LDS bf16x2 ----
#pragma unroll
    for (int pl = 0; pl < 2; ++pl) {
      float ls = __shfl(ph2[pl][7].y, lane - 1);
      float rs = __shfl(ph2[pl][0].x, lane + 1);
      float lb = (s == 0) ? ph2[pl][0].x : ls;
      float rb = (s == 3) ? ph2[pl][7].y : rs;
      unsigned nyp[8];
#pragma unroll
      for (int q = 0; q < 4; ++q) {
        f32x4 uv = *(const f32x4*)&phi_l[pl][ub + q * 4];
        f32x4 dv = *(const f32x4*)&phi_l[pl][db + q * 4];
#pragma unroll
        for (int e = 0; e < 2; ++e) {
          const int p = 2 * q + e;
          f32x2 u2 = (f32x2){uv[2 * e], uv[2 * e + 1]};
          f32x2 d2 = (f32x2){dv[2 * e], dv[2 * e + 1]};
          f32x2 py = (d2 - u2) * fy;
          f32x2 L = {(p == 0) ? lb : ph2[pl][p - 1].y, ph2[pl][p].x};
          f32x2 R = {ph2[pl][p].y, (p == 7) ? rb : ph2[pl][p + 1].x};
          f32x2 px = (R - L) * 0.5f;
          if (p == 0) px.x *= exl;
          if (p == 7) px.y *= exr;
          f32x2 qq = px * px + (py * py + eps2);
          f32x2 rn = {__builtin_amdgcn_rsqf(qq.x), __builtin_amdgcn_rsqf(qq.y)};
          nx2[pl][p] = px * rn;
          f32x2 nyv = py * rn;
          nyp[p] = cvt_pk_bf16(nyv.x, nyv.y);
        }
      }
      *(uint4*)&ny_l[pl][myn]     = make_uint4(nyp[0], nyp[1], nyp[2], nyp[3]);
      *(uint4*)&ny_l[pl][myn + 4] = make_uint4(nyp[4], nyp[5], nyp[6], nyp[7]);
    }
    __syncthreads();

    // ---- pass 2 (both planes): curvature + update + incremental sums ----
    float inc_at[2], inc_iat[2];
#pragma unroll
    for (int pl = 0; pl < 2; ++pl) {
      float nls = __shfl(nx2[pl][7].y, lane - 1);
      float nrs = __shfl(nx2[pl][0].x, lane + 1);
      float nlb = (s == 0) ? nx2[pl][0].x : nls;
      float nrb = (s == 3) ? nx2[pl][7].y : nrs;
      f32x2 ia2 = {0.f, 0.f}, ii2 = {0.f, 0.f};
#pragma unroll
      for (int h = 0; h < 2; ++h) {
        uint4 au = *(const uint4*)&ny_l[pl][ubn + 4 * h];
        uint4 ad = *(const uint4*)&ny_l[pl][dbn + 4 * h];
        unsigned ua[4] = {au.x, au.y, au.z, au.w};
        unsigned ud[4] = {ad.x, ad.y, ad.z, ad.w};
        f32x2 phs[4];
#pragma unroll
        for (int e = 0; e < 4; ++e) {
          const int p = 4 * h + e;
          f32x2 nyu = {__uint_as_float(ua[e] << 16), __uint_as_float(ua[e] & 0xffff0000u)};
          f32x2 nyd = {__uint_as_float(ud[e] << 16), __uint_as_float(ud[e] & 0xffff0000u)};
          f32x2 dny = (nyd - nyu) * fy;
          f32x2 L = {(p == 0) ? nlb : nx2[pl][p - 1].y, nx2[pl][p].x};
          f32x2 R = {nx2[pl][p].y, (p == 7) ? nrb : nx2[pl][p + 1].x};
          f32x2 dnx = (R - L) * 0.5f;
          if (p == 0) dnx.x *= exl;
          if (p == 7) dnx.y *= exr;
          f32x2 curv = dnx + dny;
          f32x2 c = ph2[pl][p];
          f32x2 den = c * c + (f32x2){1.f, 1.f};
          f32x2 rcd = {__builtin_amdgcn_rcpf(den.x), __builtin_amdgcn_rcpf(den.y)};
          f32x2 tI = I2[pl][p] * 2.f + (f32x2){ms12[pl], ms12[pl]};
          f32x2 force = tI * lam12[pl] + curv;
          f32x2 dphi = (rcd * dtpi) * force;
          f32x2 pn = c + dphi;
          ph2[pl][p] = pn;
          phs[e] = pn;
          f32x2 da = dphi * rcd;
          ia2 += da;
          ii2 = I2[pl][p] * da + ii2;
        }
        if (it < 9) {
          *(f32x4*)&phi_l[pl][my + 8 * h] =
              (f32x4){phs[0].x, phs[0].y, phs[1].x, phs[1].y};
          *(f32x4*)&phi_l[pl][my + 8 * h + 4] =
              (f32x4){phs[2].x, phs[2].y, phs[3].x, phs[3].y};
        }
      }
      inc_at[pl] = ia2.x + ia2.y;
      inc_iat[pl] = ii2.x + ii2.y;
    }
    if (it < 9) {
#pragma unroll
      for (int off = 32; off; off >>= 1) {
        inc_at[0] += __shfl_xor(inc_at[0], off);
        inc_iat[0] += __shfl_xor(inc_iat[0], off);
        inc_at[1] += __shfl_xor(inc_at[1], off);
        inc_iat[1] += __shfl_xor(inc_iat[1], off);
      }
      if (lane == 0) {
        red[wv * 4 + 0] = inc_at[0];
        red[wv * 4 + 1] = inc_iat[0];
        red[wv * 4 + 2] = inc_at[1];
        red[wv * 4 + 3] = inc_iat[1];
      }
      __syncthreads();
#pragma unroll
      for (int pl = 0; pl < 2; ++pl) {
        S_at[pl]  += red[pl*2+0] + red[pl*2+4] + red[pl*2+8] + red[pl*2+12];
        S_iat[pl] += red[pl*2+1] + red[pl*2+5] + red[pl*2+9] + red[pl*2+13];
      }
    }
  }

#pragma unroll
  for (int pl = 0; pl < 2; ++pl) {
    const size_t gb = pl ? gb1 : gb0;
#pragma unroll
    for (int q = 0; q < 4; ++q) {
      f32x2 pa = ph2[pl][2 * q], pb2 = ph2[pl][2 * q + 1];
      float o0 = 1.f / (1.f + exp2f(pa.x * -1.44269504089f));
      float o1 = 1.f / (1.f + exp2f(pa.y * -1.44269504089f));
      float o2 = 1.f / (1.f + exp2f(pb2.x * -1.44269504089f));
      float o3 = 1.f / (1.f + exp2f(pb2.y * -1.44269504089f));
      *(float4*)(ob + gb + q * 4) = make_float4(o0, o1, o2, o3);
    }
  }
}

extern "C" void kernel_launch(void* const* d_in, const int* in_sizes, int n_in,
                              void* d_out, int out_size, void* d_ws, size_t ws_size,
                              hipStream_t stream)
{
  const float* contour = (const float*)d_in[0];
  const float* g       = (const float*)d_in[1];
  const float* x       = (const float*)d_in[2];
  const float* dt      = (const float*)d_in[3];
  const float* lam     = (const float*)d_in[4];
  const float* g_w     = (const float*)d_in[5];
  const float* x_w     = (const float*)d_in[6];
  const float* c_w     = (const float*)d_in[7];
  float* out = (float*)d_out;
  float* z   = (float*)d_ws;                       // [8,512,64,64] f32 = 64 MiB
  ushort* WH = (ushort*)(z + (size_t)8 * O_CH * PIX);  // +64 MiB
  ushort* WL = WH + W_ELEMS;                       // +1.25 MiB

  conv_w<<<dim3(256, 3), dim3(256), 0, stream>>>(g_w, x_w, c_w, WH, WL);
  mfma_gemm_all<<<dim3(32, 4, 16), dim3(512), 0, stream>>>(
      g, x, contour, WH, WL, z, out);
  chanvese<<<dim3(2048), dim3(256), 0, stream>>>(z, out, dt, lam);
}

// Round 17
// 248.198 us; speedup vs baseline: 1.0805x; 1.0805x over previous
//
#include <hip/hip_runtime.h>
#include <math.h>

#define PIX 4096
#define O_CH 512
#define CV_PITCH 68   // f32 words per row in LDS (64 data + 4 pad)

// bf16 weight-plane offsets (ushorts): g[512x256], x[512x512], c[512x256]
#define WOFF_G 0
#define WOFF_X 131072
#define WOFF_C 393216
#define W_ELEMS 524288

typedef __attribute__((ext_vector_type(8))) short s16x8;
typedef __attribute__((ext_vector_type(4))) float f32x4;
typedef __attribute__((ext_vector_type(2))) float f32x2;

__device__ __forceinline__ unsigned cvt_pk_bf16(float a, float b) {
  unsigned r;
  asm("v_cvt_pk_bf16_f32 %0, %1, %2" : "=v"(r) : "v"(a), "v"(b));
  return r;
}

// ---------------- weight pre-conversion: f32 -> bf16 hi/lo planes ----------------
// Output layout: per 128x64 tile (tile_id = ot*ktiles + kt), the 8192 ushorts
// are stored EXACTLY in the GEMM's swizzled-LDS order:
//   global[tile*8192 + o_r*64 + ((j^(o_r&7))<<3) + e] = W[ot*128+o_r][kt*64 + j*8 + e]
// so the GEMM W-stage is a pure linear copy (bit-identical LDS content).
__global__ __launch_bounds__(256) void conv_w(
    const float* __restrict__ gw, const float* __restrict__ xw,
    const float* __restrict__ cw,
    ushort* __restrict__ WH, ushort* __restrict__ WL)
{
  const int r = blockIdx.y;
  const float* src = (r == 0) ? gw : ((r == 1) ? xw : cw);
  const int Kk = (r == 1) ? 512 : 256;
  const int ktiles = Kk >> 6;
  const int nunits = (r == 1) ? 32768 : 16384;   // ushort8 units
  const int doff = (r == 0) ? WOFF_G : ((r == 1) ? WOFF_X : WOFF_C);
  const int u = blockIdx.x * 256 + threadIdx.x;
  if (u >= nunits) return;
  const int tile = u >> 10;          // 1024 units per tile
  const int w = u & 1023;
  const int o_r = w >> 3;
  const int jx = w & 7;
  const int j = jx ^ (o_r & 7);
  const int ot = tile / ktiles, kt = tile - ot * ktiles;
  const float* s = src + (size_t)(ot * 128 + o_r) * Kk + kt * 64 + j * 8;
  float4 v0 = *(const float4*)s;
  float4 v1 = *(const float4*)(s + 4);
  float vv[8] = {v0.x, v0.y, v0.z, v0.w, v1.x, v1.y, v1.z, v1.w};
  unsigned h[4], l[4];
#pragma unroll
  for (int j2 = 0; j2 < 4; ++j2) {
    h[j2] = cvt_pk_bf16(vv[2 * j2], vv[2 * j2 + 1]);
    float lo0 = vv[2 * j2] - __uint_as_float(h[j2] << 16);
    float lo1 = vv[2 * j2 + 1] - __uint_as_float(h[j2] & 0xffff0000u);
    l[j2] = cvt_pk_bf16(lo0, lo1);
  }
  const size_t dst = (size_t)doff + (size_t)tile * 8192 + (size_t)w * 8;
  *(uint4*)(WH + dst) = make_uint4(h[0], h[1], h[2], h[3]);
  *(uint4*)(WL + dst) = make_uint4(l[0], l[1], l[2], l[3]);
}

// ---------------- merged MFMA GEMM (split-bf16), 512-thread / 8-wave blocks ----
// bz<8: z[b] = relu(g_w*g[b]) + x_w*x[b];  bz>=8: phi0[b] = c_w*contour[b]
__global__ __launch_bounds__(512, 4) void mfma_gemm_all(
    const float* __restrict__ g, const float* __restrict__ x,
    const float* __restrict__ contour,
    const ushort* __restrict__ WHg, const ushort* __restrict__ WLg,
    float* __restrict__ z, float* __restrict__ phi0)
{
  __shared__ ushort WHs[8192], WLs[8192], AHs[8192], ALs[8192];  // 64 KB
  const int t = threadIdx.x;
  const int lane = t & 63, wave = t >> 6;   // 8 waves
  const int wm = wave & 1, wn = wave >> 1;  // 2 x 4 wave grid
  const int rowA = lane & 15, kg = lane >> 4;
  const int aph = wave & 1;                 // A-stage: p-half this wave covers
  const int akg = wave >> 1;                // A-stage: k-subgroup 0..3
  const int pb = blockIdx.x * 128, ob = blockIdx.y * 128;
  const int bz = blockIdx.z;
  const bool isZ = bz < 8;
  const int b = isZ ? bz : bz - 8;

  const int woff1 = isZ ? WOFF_G : WOFF_C;
  const float* A1 = (isZ ? g : contour) + (size_t)b * 256 * PIX;
  const float* A2 = x + (size_t)(isZ ? b : 0) * 512 * PIX;  // used only when isZ
  float* out = (isZ ? z : phi0) + (size_t)b * O_CH * PIX;
  const int nsteps = isZ ? 12 : 4;

  f32x4 acc[4][2];
#pragma unroll
  for (int mi = 0; mi < 4; ++mi)
#pragma unroll
    for (int ni = 0; ni < 2; ++ni) acc[mi][ni] = (f32x4){0.f, 0.f, 0.f, 0.f};

  float pf[2][8];   // prefetched A values for the CURRENT step: [ch][j]

  {
    const float* acp = A1 + pb + aph * 64 + lane;
#pragma unroll
    for (int ch = 0; ch < 2; ++ch)
#pragma unroll
      for (int j = 0; j < 8; ++j)
        pf[ch][j] = acp[(size_t)(ch * 32 + akg * 8 + j) * PIX];
  }

  for (int st = 0; st < nsteps; ++st) {
    const bool s2 = st >= 4;
    const int K = s2 ? 512 : 256;
    const int woff = s2 ? WOFF_X : woff1;

    // ---- stage W tile: pure linear copy from pre-swizzled planes ----
    {
      const int ktiles = K >> 6;
      const int kt = s2 ? (st - 4) : st;
      const size_t tb = (size_t)woff + ((size_t)blockIdx.y * ktiles + kt) * 8192;
      const int ci = t * 16;   // 512 threads x 16 ushorts = 8192
      *(s16x8*)&WHs[ci]     = *(const s16x8*)(WHg + tb + ci);
      *(s16x8*)&WHs[ci + 8] = *(const s16x8*)(WHg + tb + ci + 8);
      *(s16x8*)&WLs[ci]     = *(const s16x8*)(WLg + tb + ci);
      *(s16x8*)&WLs[ci + 8] = *(const s16x8*)(WLg + tb + ci + 8);
    }
    // ---- convert current pf -> LDS (hi/lo, swizzled) ----
    {
      const int rp = aph * 64 + lane;
#pragma unroll
      for (int ch = 0; ch < 2; ++ch) {
        unsigned h[4], l[4];
#pragma unroll
        for (int j2 = 0; j2 < 4; ++j2) {
          float v0 = pf[ch][2 * j2], v1 = pf[ch][2 * j2 + 1];
          h[j2] = cvt_pk_bf16(v0, v1);
          float lo0 = v0 - __uint_as_float(h[j2] << 16);
          float lo1 = v1 - __uint_as_float(h[j2] & 0xffff0000u);
          l[j2] = cvt_pk_bf16(lo0, lo1);
        }
        int grp = ch * 4 + akg;
        int idx = rp * 64 + ((grp ^ (rp & 7)) << 3);
        *(uint4*)&AHs[idx] = make_uint4(h[0], h[1], h[2], h[3]);
        *(uint4*)&ALs[idx] = make_uint4(l[0], l[1], l[2], l[3]);
      }
    }
    __syncthreads();

    if (st + 1 < nsteps) {
      const bool n2 = (st + 1) >= 4;
      const float* Ab = n2 ? A2 : A1;
      const int kbn = (n2 ? st + 1 - 4 : st + 1) * 64;
      const float* acp = Ab + (size_t)kbn * PIX + pb + aph * 64 + lane;
#pragma unroll
      for (int ch = 0; ch < 2; ++ch)
#pragma unroll
        for (int j = 0; j < 8; ++j)
          pf[ch][j] = acp[(size_t)(ch * 32 + akg * 8 + j) * PIX];
    }

#pragma unroll
    for (int ks = 0; ks < 2; ++ks) {
      s16x8 wh[4], wlv[4], ah[2], alv[2];
#pragma unroll
      for (int mi = 0; mi < 4; ++mi) {
        int row = wm * 64 + mi * 16 + rowA;
        int idx = row * 64 + (((ks * 4 + kg) ^ (row & 7)) << 3);
        wh[mi]  = *(const s16x8*)&WHs[idx];
        wlv[mi] = *(const s16x8*)&WLs[idx];
      }
#pragma unroll
      for (int ni = 0; ni < 2; ++ni) {
        int row = wn * 32 + ni * 16 + rowA;
        int idx = row * 64 + (((ks * 4 + kg) ^ (row & 7)) << 3);
        ah[ni]  = *(const s16x8*)&AHs[idx];
        alv[ni] = *(const s16x8*)&ALs[idx];
      }
#pragma unroll
      for (int mi = 0; mi < 4; ++mi)
#pragma unroll
        for (int ni = 0; ni < 2; ++ni) {
          acc[mi][ni] = __builtin_amdgcn_mfma_f32_16x16x32_bf16(wh[mi],  ah[ni],  acc[mi][ni], 0, 0, 0);
          acc[mi][ni] = __builtin_amdgcn_mfma_f32_16x16x32_bf16(wh[mi],  alv[ni], acc[mi][ni], 0, 0, 0);
          acc[mi][ni] = __builtin_amdgcn_mfma_f32_16x16x32_bf16(wlv[mi], ah[ni],  acc[mi][ni], 0, 0, 0);
        }
    }
    if (isZ && st == 3) {
#pragma unroll
      for (int mi = 0; mi < 4; ++mi)
#pragma unroll
        for (int ni = 0; ni < 2; ++ni)
#pragma unroll
          for (int r = 0; r < 4; ++r) acc[mi][ni][r] = fmaxf(acc[mi][ni][r], 0.f);
    }
    __syncthreads();
  }

  const int orow = (lane >> 4) * 4, pcol = lane & 15;
#pragma unroll
  for (int mi = 0; mi < 4; ++mi)
#pragma unroll
    for (int ni = 0; ni < 2; ++ni)
#pragma unroll
      for (int r = 0; r < 4; ++r)
        out[(size_t)(ob + wm * 64 + mi * 16 + orow + r) * PIX +
            pb + wn * 32 + ni * 16 + pcol] = acc[mi][ni][r];
}

// ---------------- Chan-Vese: 256 threads, 16 px/thread, ny f32 in LDS ----------------
__device__ __forceinline__ float fast_atan(float x) {
  float a = __builtin_fabsf(x);
  float inv = __builtin_amdgcn_rcpf(a);
  bool big = a > 1.f;
  float tt = big ? inv : a;
  float t2 = tt * tt;
  float p = fmaf(t2, 0.0208351f, -0.0851330f);
  p = fmaf(t2, p, 0.1801410f);
  p = fmaf(t2, p, -0.3302995f);
  p = fmaf(t2, p, 0.9998660f);
  p = p * tt;
  float r = big ? (1.57079632679f - p) : p;
  return __builtin_copysignf(r, x);
}

// Best-known chanvese (r14/r15, 159 us). Structural knobs all closed:
// occupancy x3 null, 512-thd regress, 2-plane regress, pk-f32 asm broken.
__global__ __launch_bounds__(256, 4) void chanvese(
    const float* __restrict__ zb, float* __restrict__ ob,
    const float* __restrict__ dtp, const float* __restrict__ lamp)
{
  __shared__ float phi_l[64 * CV_PITCH];   // 17408 B
  __shared__ float ny_l[64 * CV_PITCH];    // 17408 B (f32)
  __shared__ float red[12];
  const int t = threadIdx.x;
  const int lane = t & 63, wv = t >> 6;
  const int row = t >> 2, s = t & 3;
  const size_t gbase = (size_t)blockIdx.x * PIX + row * 64 + s * 16;
  const float dtv = dtp[0], lam = lamp[0];
  const float INV_PI = 0.31830988618379067f;
  const float dtpi = dtv * INV_PI;
  const float fy = (row == 0 || row == 63) ? 1.f : 0.5f;
  const float exl = (s == 0) ? 2.f : 1.f;
  const float exr = (s == 3) ? 2.f : 1.f;
  const int my = row * CV_PITCH + s * 16;
  const int ub = ((row == 0) ? 0 : row - 1) * CV_PITCH + s * 16;
  const int db = ((row == 63) ? 63 : row + 1) * CV_PITCH + s * 16;
  const f32x2 eps2 = {1e-8f, 1e-8f};

  f32x2 I2[8], ph2[8], nx2[8];
#pragma unroll
  for (int q = 0; q < 4; ++q) {
    f32x4 iv = *(const f32x4*)(zb + gbase + q * 4);
    f32x4 pv = *(const f32x4*)(ob + gbase + q * 4);
    I2[2 * q]     = (f32x2){iv[0], iv[1]};
    I2[2 * q + 1] = (f32x2){iv[2], iv[3]};
    ph2[2 * q]     = (f32x2){pv[0], pv[1]};
    ph2[2 * q + 1] = (f32x2){pv[2], pv[3]};
    *(f32x4*)&phi_l[my + q * 4] = pv;
  }
  float sI = 0.f, s_at = 0.f, s_iat = 0.f;
#pragma unroll
  for (int p = 0; p < 8; ++p) {
    sI += I2[p].x + I2[p].y;
    float a0 = fast_atan(ph2[p].x), a1 = fast_atan(ph2[p].y);
    s_at += a0 + a1;
    s_iat = fmaf(I2[p].x, a0, fmaf(I2[p].y, a1, s_iat));
  }
#pragma unroll
  for (int off = 32; off; off >>= 1) {
    sI += __shfl_xor(sI, off);
    s_at += __shfl_xor(s_at, off);
    s_iat += __shfl_xor(s_iat, off);
  }
  if (lane == 0) { red[wv] = s_at; red[4 + wv] = s_iat; red[8 + wv] = sI; }
  __syncthreads();
  float S_at = red[0] + red[1] + red[2] + red[3];
  float S_iat = red[4] + red[5] + red[6] + red[7];
  const float sumI = red[8] + red[9] + red[10] + red[11];

  for (int it = 0; it < 10; ++it) {
    float a1 = fmaf(INV_PI, S_at, 2048.f);
    float sIH = fmaf(INV_PI, S_iat, 0.5f * sumI);
    float c1 = sIH * __builtin_amdgcn_rcpf(a1 + 1e-8f);
    float c2 = (sumI - sIH) * __builtin_amdgcn_rcpf(4096.f - a1 + 1e-8f);
    float lam12 = lam * (c1 - c2);
    float ms12 = -(c1 + c2);

    // ---- pass 1: normals; nx in regs, ny -> LDS f32 ----
    float ls = __shfl(ph2[7].y, lane - 1);
    float rs = __shfl(ph2[0].x, lane + 1);
    float lb = (s == 0) ? ph2[0].x : ls;
    float rb = (s == 3) ? ph2[7].y : rs;
#pragma unroll
    for (int q = 0; q < 4; ++q) {
      f32x4 uv = *(const f32x4*)&phi_l[ub + q * 4];
      f32x4 dv = *(const f32x4*)&phi_l[db + q * 4];
      f32x4 nyo;
#pragma unroll
      for (int e = 0; e < 2; ++e) {
        const int p = 2 * q + e;
        f32x2 u2 = (f32x2){uv[2 * e], uv[2 * e + 1]};
        f32x2 d2 = (f32x2){dv[2 * e], dv[2 * e + 1]};
        f32x2 py = (d2 - u2) * fy;
        f32x2 L = {(p == 0) ? lb : ph2[p - 1].y, ph2[p].x};
        f32x2 R = {ph2[p].y, (p == 7) ? rb : ph2[p + 1].x};
        f32x2 px = (R - L) * 0.5f;
        if (p == 0) px.x *= exl;
        if (p == 7) px.y *= exr;
        f32x2 qq = px * px + (py * py + eps2);
        f32x2 rn = {__builtin_amdgcn_rsqf(qq.x), __builtin_amdgcn_rsqf(qq.y)};
        nx2[p] = px * rn;
        f32x2 nyv = py * rn;
        nyo[2 * e] = nyv.x;
        nyo[2 * e + 1] = nyv.y;
      }
      *(f32x4*)&ny_l[my + q * 4] = nyo;
    }
    __syncthreads();

    // ---- pass 2: curvature + update + incremental sums ----
    float nls = __shfl(nx2[7].y, lane - 1);
    float nrs = __shfl(nx2[0].x, lane + 1);
    float nlb = (s == 0) ? nx2[0].x : nls;
    float nrb = (s == 3) ? nx2[7].y : nrs;
    f32x2 inc_at2 = {0.f, 0.f}, inc_iat2 = {0.f, 0.f};
#pragma unroll
    for (int q = 0; q < 4; ++q) {
      f32x4 au = *(const f32x4*)&ny_l[ub + q * 4];
      f32x4 ad = *(const f32x4*)&ny_l[db + q * 4];
      f32x4 pho;
#pragma unroll
      for (int e = 0; e < 2; ++e) {
        const int p = 2 * q + e;
        f32x2 nyu = (f32x2){au[2 * e], au[2 * e + 1]};
        f32x2 nyd = (f32x2){ad[2 * e], ad[2 * e + 1]};
        f32x2 dny = (nyd - nyu) * fy;
        f32x2 L = {(p == 0) ? nlb : nx2[p - 1].y, nx2[p].x};
        f32x2 R = {nx2[p].y, (p == 7) ? nrb : nx2[p + 1].x};
        f32x2 dnx = (R - L) * 0.5f;
        if (p == 0) dnx.x *= exl;
        if (p == 7) dnx.y *= exr;
        f32x2 curv = dnx + dny;
        f32x2 c = ph2[p];
        f32x2 den = c * c + (f32x2){1.f, 1.f};
        f32x2 rcd = {__builtin_amdgcn_rcpf(den.x), __builtin_amdgcn_rcpf(den.y)};
        f32x2 tI = I2[p] * 2.f + (f32x2){ms12, ms12};
        f32x2 force = tI * lam12 + curv;
        f32x2 dphi = (rcd * dtpi) * force;
        f32x2 pn = c + dphi;
        ph2[p] = pn;
        pho[2 * e] = pn.x;
        pho[2 * e + 1] = pn.y;
        f32x2 da = dphi * rcd;
        inc_at2 += da;
        inc_iat2 = I2[p] * da + inc_iat2;
      }
      if (it < 9) *(f32x4*)&phi_l[my + q * 4] = pho;
    }
    if (it < 9) {
      float inc_at = inc_at2.x + inc_at2.y;
      float inc_iat = inc_iat2.x + inc_iat2.y;
#pragma unroll
      for (int off = 32; off; off >>= 1) {
        inc_at += __shfl_xor(inc_at, off);
        inc_iat += __shfl_xor(inc_iat, off);
      }
      if (lane == 0) { red[2 * wv] = inc_at; red[2 * wv + 1] = inc_iat; }
      __syncthreads();
      S_at += red[0] + red[2] + red[4] + red[6];
      S_iat += red[1] + red[3] + red[5] + red[7];
    }
  }

#pragma unroll
  for (int q = 0; q < 4; ++q) {
    f32x2 pa = ph2[2 * q], pb2 = ph2[2 * q + 1];
    float o0 = 1.f / (1.f + exp2f(pa.x * -1.44269504089f));
    float o1 = 1.f / (1.f + exp2f(pa.y * -1.44269504089f));
    float o2 = 1.f / (1.f + exp2f(pb2.x * -1.44269504089f));
    float o3 = 1.f / (1.f + exp2f(pb2.y * -1.44269504089f));
    *(float4*)(ob + gbase + q * 4) = make_float4(o0, o1, o2, o3);
  }
}

extern "C" void kernel_launch(void* const* d_in, const int* in_sizes, int n_in,
                              void* d_out, int out_size, void* d_ws, size_t ws_size,
                              hipStream_t stream)
{
  const float* contour = (const float*)d_in[0];
  const float* g       = (const float*)d_in[1];
  const float* x       = (const float*)d_in[2];
  const float* dt      = (const float*)d_in[3];
  const float* lam     = (const float*)d_in[4];
  const float* g_w     = (const float*)d_in[5];
  const float* x_w     = (const float*)d_in[6];
  const float* c_w     = (const float*)d_in[7];
  float* out = (float*)d_out;
  float* z   = (float*)d_ws;                       // [8,512,64,64] f32 = 64 MiB
  ushort* WH = (ushort*)(z + (size_t)8 * O_CH * PIX);  // +64 MiB
  ushort* WL = WH + W_ELEMS;                       // +1.25 MiB

  conv_w<<<dim3(128, 3), dim3(256), 0, stream>>>(g_w, x_w, c_w, WH, WL);
  mfma_gemm_all<<<dim3(32, 4, 16), dim3(512), 0, stream>>>(
      g, x, contour, WH, WL, z, out);
  chanvese<<<dim3(4096), dim3(256), 0, stream>>>(z, out, dt, lam);
}

// Round 18
// 243.498 us; speedup vs baseline: 1.1014x; 1.0193x over previous
//
#include <hip/hip_runtime.h>
#include <math.h>

#define PIX 4096
#define O_CH 512
#define CV_PITCH 68   // f32 words per row in LDS (64 data + 4 pad)

// bf16 weight-plane offsets (ushorts): g[512x256], x[512x512], c[512x256]
#define WOFF_G 0
#define WOFF_X 131072
#define WOFF_C 393216
#define W_ELEMS 524288

typedef __attribute__((ext_vector_type(8))) short s16x8;
typedef __attribute__((ext_vector_type(4))) float f32x4;
typedef __attribute__((ext_vector_type(2))) float f32x2;

typedef const __attribute__((address_space(1))) unsigned GlobU;
typedef __attribute__((address_space(3))) unsigned LdsU;

__device__ __forceinline__ unsigned cvt_pk_bf16(float a, float b) {
  unsigned r;
  asm("v_cvt_pk_bf16_f32 %0, %1, %2" : "=v"(r) : "v"(a), "v"(b));
  return r;
}

// ---------------- weight pre-conversion: f32 -> bf16 hi/lo planes ----------------
// Output layout: per 128x64 tile (tile_id = ot*ktiles + kt), the 8192 ushorts
// are stored EXACTLY in the GEMM's swizzled-LDS order:
//   global[tile*8192 + o_r*64 + ((j^(o_r&7))<<3) + e] = W[ot*128+o_r][kt*64 + j*8 + e]
// so the GEMM W-stage is a pure linear copy (global_load_lds compatible).
__global__ __launch_bounds__(256) void conv_w(
    const float* __restrict__ gw, const float* __restrict__ xw,
    const float* __restrict__ cw,
    ushort* __restrict__ WH, ushort* __restrict__ WL)
{
  const int r = blockIdx.y;
  const float* src = (r == 0) ? gw : ((r == 1) ? xw : cw);
  const int Kk = (r == 1) ? 512 : 256;
  const int ktiles = Kk >> 6;
  const int nunits = (r == 1) ? 32768 : 16384;   // ushort8 units
  const int doff = (r == 0) ? WOFF_G : ((r == 1) ? WOFF_X : WOFF_C);
  const int u = blockIdx.x * 256 + threadIdx.x;
  if (u >= nunits) return;
  const int tile = u >> 10;          // 1024 units per tile
  const int w = u & 1023;
  const int o_r = w >> 3;
  const int jx = w & 7;
  const int j = jx ^ (o_r & 7);
  const int ot = tile / ktiles, kt = tile - ot * ktiles;
  const float* s = src + (size_t)(ot * 128 + o_r) * Kk + kt * 64 + j * 8;
  float4 v0 = *(const float4*)s;
  float4 v1 = *(const float4*)(s + 4);
  float vv[8] = {v0.x, v0.y, v0.z, v0.w, v1.x, v1.y, v1.z, v1.w};
  unsigned h[4], l[4];
#pragma unroll
  for (int j2 = 0; j2 < 4; ++j2) {
    h[j2] = cvt_pk_bf16(vv[2 * j2], vv[2 * j2 + 1]);
    float lo0 = vv[2 * j2] - __uint_as_float(h[j2] << 16);
    float lo1 = vv[2 * j2 + 1] - __uint_as_float(h[j2] & 0xffff0000u);
    l[j2] = cvt_pk_bf16(lo0, lo1);
  }
  const size_t dst = (size_t)doff + (size_t)tile * 8192 + (size_t)w * 8;
  *(uint4*)(WH + dst) = make_uint4(h[0], h[1], h[2], h[3]);
  *(uint4*)(WL + dst) = make_uint4(l[0], l[1], l[2], l[3]);
}

// ---------------- merged MFMA GEMM (split-bf16), 512-thread / 8-wave blocks ----
// bz<8: z[b] = relu(g_w*g[b]) + x_w*x[b];  bz>=8: phi0[b] = c_w*contour[b]
// W-stage uses global_load_lds (16B): async direct-to-LDS, no VGPR round-trip.
__global__ __launch_bounds__(512, 4) void mfma_gemm_all(
    const float* __restrict__ g, const float* __restrict__ x,
    const float* __restrict__ contour,
    const ushort* __restrict__ WHg, const ushort* __restrict__ WLg,
    float* __restrict__ z, float* __restrict__ phi0)
{
  __shared__ ushort WHs[8192], WLs[8192], AHs[8192], ALs[8192];  // 64 KB
  const int t = threadIdx.x;
  const int lane = t & 63, wave = t >> 6;   // 8 waves
  const int wm = wave & 1, wn = wave >> 1;  // 2 x 4 wave grid
  const int rowA = lane & 15, kg = lane >> 4;
  const int aph = wave & 1;                 // A-stage: p-half this wave covers
  const int akg = wave >> 1;                // A-stage: k-subgroup 0..3
  const int pb = blockIdx.x * 128, ob = blockIdx.y * 128;
  const int bz = blockIdx.z;
  const bool isZ = bz < 8;
  const int b = isZ ? bz : bz - 8;

  const int woff1 = isZ ? WOFF_G : WOFF_C;
  const float* A1 = (isZ ? g : contour) + (size_t)b * 256 * PIX;
  const float* A2 = x + (size_t)(isZ ? b : 0) * 512 * PIX;  // used only when isZ
  float* out = (isZ ? z : phi0) + (size_t)b * O_CH * PIX;
  const int nsteps = isZ ? 12 : 4;

  f32x4 acc[4][2];
#pragma unroll
  for (int mi = 0; mi < 4; ++mi)
#pragma unroll
    for (int ni = 0; ni < 2; ++ni) acc[mi][ni] = (f32x4){0.f, 0.f, 0.f, 0.f};

  float pf[2][8];   // prefetched A values for the CURRENT step: [ch][j]

  {
    const float* acp = A1 + pb + aph * 64 + lane;
#pragma unroll
    for (int ch = 0; ch < 2; ++ch)
#pragma unroll
      for (int j = 0; j < 8; ++j)
        pf[ch][j] = acp[(size_t)(ch * 32 + akg * 8 + j) * PIX];
  }

  for (int st = 0; st < nsteps; ++st) {
    const bool s2 = st >= 4;
    const int K = s2 ? 512 : 256;
    const int woff = s2 ? WOFF_X : woff1;

    // ---- stage W tile: async global->LDS copy from pre-swizzled planes ----
    // Each wave covers regions (2w) and (2w+1) of 1KB (64 lanes x 16B) per
    // plane. LDS dest = wave-uniform base + lane*16B (HW semantics); the
    // per-lane GLOBAL address selects the matching 8 ushorts.
    {
      const int ktiles = K >> 6;
      const int kt = s2 ? (st - 4) : st;
      const size_t tb = (size_t)woff + ((size_t)blockIdx.y * ktiles + kt) * 8192;
      const int r0 = wave * 1024 + lane * 8;        // region 2w, lane slot
      const int r1 = wave * 1024 + 512 + lane * 8;  // region 2w+1
      __builtin_amdgcn_global_load_lds((GlobU*)(WHg + tb + r0), (LdsU*)&WHs[wave * 1024], 16, 0, 0);
      __builtin_amdgcn_global_load_lds((GlobU*)(WHg + tb + r1), (LdsU*)&WHs[wave * 1024 + 512], 16, 0, 0);
      __builtin_amdgcn_global_load_lds((GlobU*)(WLg + tb + r0), (LdsU*)&WLs[wave * 1024], 16, 0, 0);
      __builtin_amdgcn_global_load_lds((GlobU*)(WLg + tb + r1), (LdsU*)&WLs[wave * 1024 + 512], 16, 0, 0);
    }
    // ---- convert current pf -> LDS (hi/lo, swizzled) ----
    {
      const int rp = aph * 64 + lane;
#pragma unroll
      for (int ch = 0; ch < 2; ++ch) {
        unsigned h[4], l[4];
#pragma unroll
        for (int j2 = 0; j2 < 4; ++j2) {
          float v0 = pf[ch][2 * j2], v1 = pf[ch][2 * j2 + 1];
          h[j2] = cvt_pk_bf16(v0, v1);
          float lo0 = v0 - __uint_as_float(h[j2] << 16);
          float lo1 = v1 - __uint_as_float(h[j2] & 0xffff0000u);
          l[j2] = cvt_pk_bf16(lo0, lo1);
        }
        int grp = ch * 4 + akg;
        int idx = rp * 64 + ((grp ^ (rp & 7)) << 3);
        *(uint4*)&AHs[idx] = make_uint4(h[0], h[1], h[2], h[3]);
        *(uint4*)&ALs[idx] = make_uint4(l[0], l[1], l[2], l[3]);
      }
    }
    __syncthreads();

    if (st + 1 < nsteps) {
      const bool n2 = (st + 1) >= 4;
      const float* Ab = n2 ? A2 : A1;
      const int kbn = (n2 ? st + 1 - 4 : st + 1) * 64;
      const float* acp = Ab + (size_t)kbn * PIX + pb + aph * 64 + lane;
#pragma unroll
      for (int ch = 0; ch < 2; ++ch)
#pragma unroll
        for (int j = 0; j < 8; ++j)
          pf[ch][j] = acp[(size_t)(ch * 32 + akg * 8 + j) * PIX];
    }

#pragma unroll
    for (int ks = 0; ks < 2; ++ks) {
      s16x8 wh[4], wlv[4], ah[2], alv[2];
#pragma unroll
      for (int mi = 0; mi < 4; ++mi) {
        int row = wm * 64 + mi * 16 + rowA;
        int idx = row * 64 + (((ks * 4 + kg) ^ (row & 7)) << 3);
        wh[mi]  = *(const s16x8*)&WHs[idx];
        wlv[mi] = *(const s16x8*)&WLs[idx];
      }
#pragma unroll
      for (int ni = 0; ni < 2; ++ni) {
        int row = wn * 32 + ni * 16 + rowA;
        int idx = row * 64 + (((ks * 4 + kg) ^ (row & 7)) << 3);
        ah[ni]  = *(const s16x8*)&AHs[idx];
        alv[ni] = *(const s16x8*)&ALs[idx];
      }
#pragma unroll
      for (int mi = 0; mi < 4; ++mi)
#pragma unroll
        for (int ni = 0; ni < 2; ++ni) {
          acc[mi][ni] = __builtin_amdgcn_mfma_f32_16x16x32_bf16(wh[mi],  ah[ni],  acc[mi][ni], 0, 0, 0);
          acc[mi][ni] = __builtin_amdgcn_mfma_f32_16x16x32_bf16(wh[mi],  alv[ni], acc[mi][ni], 0, 0, 0);
          acc[mi][ni] = __builtin_amdgcn_mfma_f32_16x16x32_bf16(wlv[mi], ah[ni],  acc[mi][ni], 0, 0, 0);
        }
    }
    if (isZ && st == 3) {
#pragma unroll
      for (int mi = 0; mi < 4; ++mi)
#pragma unroll
        for (int ni = 0; ni < 2; ++ni)
#pragma unroll
          for (int r = 0; r < 4; ++r) acc[mi][ni][r] = fmaxf(acc[mi][ni][r], 0.f);
    }
    __syncthreads();
  }

  const int orow = (lane >> 4) * 4, pcol = lane & 15;
#pragma unroll
  for (int mi = 0; mi < 4; ++mi)
#pragma unroll
    for (int ni = 0; ni < 2; ++ni)
#pragma unroll
      for (int r = 0; r < 4; ++r)
        out[(size_t)(ob + wm * 64 + mi * 16 + orow + r) * PIX +
            pb + wn * 32 + ni * 16 + pcol] = acc[mi][ni][r];
}

// ---------------- Chan-Vese: 256 threads, 16 px/thread, ny f32 in LDS ----------------
__device__ __forceinline__ float fast_atan(float x) {
  float a = __builtin_fabsf(x);
  float inv = __builtin_amdgcn_rcpf(a);
  bool big = a > 1.f;
  float tt = big ? inv : a;
  float t2 = tt * tt;
  float p = fmaf(t2, 0.0208351f, -0.0851330f);
  p = fmaf(t2, p, 0.1801410f);
  p = fmaf(t2, p, -0.3302995f);
  p = fmaf(t2, p, 0.9998660f);
  p = p * tt;
  float r = big ? (1.57079632679f - p) : p;
  return __builtin_copysignf(r, x);
}

// Best-known chanvese (r14/r15, 159 us). Structural knobs all closed:
// occupancy x3 null, 512-thd regress, 2-plane regress, pk-f32 asm broken.
__global__ __launch_bounds__(256, 4) void chanvese(
    const float* __restrict__ zb, float* __restrict__ ob,
    const float* __restrict__ dtp, const float* __restrict__ lamp)
{
  __shared__ float phi_l[64 * CV_PITCH];   // 17408 B
  __shared__ float ny_l[64 * CV_PITCH];    // 17408 B (f32)
  __shared__ float red[12];
  const int t = threadIdx.x;
  const int lane = t & 63, wv = t >> 6;
  const int row = t >> 2, s = t & 3;
  const size_t gbase = (size_t)blockIdx.x * PIX + row * 64 + s * 16;
  const float dtv = dtp[0], lam = lamp[0];
  const float INV_PI = 0.31830988618379067f;
  const float dtpi = dtv * INV_PI;
  const float fy = (row == 0 || row == 63) ? 1.f : 0.5f;
  const float exl = (s == 0) ? 2.f : 1.f;
  const float exr = (s == 3) ? 2.f : 1.f;
  const int my = row * CV_PITCH + s * 16;
  const int ub = ((row == 0) ? 0 : row - 1) * CV_PITCH + s * 16;
  const int db = ((row == 63) ? 63 : row + 1) * CV_PITCH + s * 16;
  const f32x2 eps2 = {1e-8f, 1e-8f};

  f32x2 I2[8], ph2[8], nx2[8];
#pragma unroll
  for (int q = 0; q < 4; ++q) {
    f32x4 iv = *(const f32x4*)(zb + gbase + q * 4);
    f32x4 pv = *(const f32x4*)(ob + gbase + q * 4);
    I2[2 * q]     = (f32x2){iv[0], iv[1]};
    I2[2 * q + 1] = (f32x2){iv[2], iv[3]};
    ph2[2 * q]     = (f32x2){pv[0], pv[1]};
    ph2[2 * q + 1] = (f32x2){pv[2], pv[3]};
    *(f32x4*)&phi_l[my + q * 4] = pv;
  }
  float sI = 0.f, s_at = 0.f, s_iat = 0.f;
#pragma unroll
  for (int p = 0; p < 8; ++p) {
    sI += I2[p].x + I2[p].y;
    float a0 = fast_atan(ph2[p].x), a1 = fast_atan(ph2[p].y);
    s_at += a0 + a1;
    s_iat = fmaf(I2[p].x, a0, fmaf(I2[p].y, a1, s_iat));
  }
#pragma unroll
  for (int off = 32; off; off >>= 1) {
    sI += __shfl_xor(sI, off);
    s_at += __shfl_xor(s_at, off);
    s_iat += __shfl_xor(s_iat, off);
  }
  if (lane == 0) { red[wv] = s_at; red[4 + wv] = s_iat; red[8 + wv] = sI; }
  __syncthreads();
  float S_at = red[0] + red[1] + red[2] + red[3];
  float S_iat = red[4] + red[5] + red[6] + red[7];
  const float sumI = red[8] + red[9] + red[10] + red[11];

  for (int it = 0; it < 10; ++it) {
    float a1 = fmaf(INV_PI, S_at, 2048.f);
    float sIH = fmaf(INV_PI, S_iat, 0.5f * sumI);
    float c1 = sIH * __builtin_amdgcn_rcpf(a1 + 1e-8f);
    float c2 = (sumI - sIH) * __builtin_amdgcn_rcpf(4096.f - a1 + 1e-8f);
    float lam12 = lam * (c1 - c2);
    float ms12 = -(c1 + c2);

    // ---- pass 1: normals; nx in regs, ny -> LDS f32 ----
    float ls = __shfl(ph2[7].y, lane - 1);
    float rs = __shfl(ph2[0].x, lane + 1);
    float lb = (s == 0) ? ph2[0].x : ls;
    float rb = (s == 3) ? ph2[7].y : rs;
#pragma unroll
    for (int q = 0; q < 4; ++q) {
      f32x4 uv = *(const f32x4*)&phi_l[ub + q * 4];
      f32x4 dv = *(const f32x4*)&phi_l[db + q * 4];
      f32x4 nyo;
#pragma unroll
      for (int e = 0; e < 2; ++e) {
        const int p = 2 * q + e;
        f32x2 u2 = (f32x2){uv[2 * e], uv[2 * e + 1]};
        f32x2 d2 = (f32x2){dv[2 * e], dv[2 * e + 1]};
        f32x2 py = (d2 - u2) * fy;
        f32x2 L = {(p == 0) ? lb : ph2[p - 1].y, ph2[p].x};
        f32x2 R = {ph2[p].y, (p == 7) ? rb : ph2[p + 1].x};
        f32x2 px = (R - L) * 0.5f;
        if (p == 0) px.x *= exl;
        if (p == 7) px.y *= exr;
        f32x2 qq = px * px + (py * py + eps2);
        f32x2 rn = {__builtin_amdgcn_rsqf(qq.x), __builtin_amdgcn_rsqf(qq.y)};
        nx2[p] = px * rn;
        f32x2 nyv = py * rn;
        nyo[2 * e] = nyv.x;
        nyo[2 * e + 1] = nyv.y;
      }
      *(f32x4*)&ny_l[my + q * 4] = nyo;
    }
    __syncthreads();

    // ---- pass 2: curvature + update + incremental sums ----
    float nls = __shfl(nx2[7].y, lane - 1);
    float nrs = __shfl(nx2[0].x, lane + 1);
    float nlb = (s == 0) ? nx2[0].x : nls;
    float nrb = (s == 3) ? nx2[7].y : nrs;
    f32x2 inc_at2 = {0.f, 0.f}, inc_iat2 = {0.f, 0.f};
#pragma unroll
    for (int q = 0; q < 4; ++q) {
      f32x4 au = *(const f32x4*)&ny_l[ub + q * 4];
      f32x4 ad = *(const f32x4*)&ny_l[db + q * 4];
      f32x4 pho;
#pragma unroll
      for (int e = 0; e < 2; ++e) {
        const int p = 2 * q + e;
        f32x2 nyu = (f32x2){au[2 * e], au[2 * e + 1]};
        f32x2 nyd = (f32x2){ad[2 * e], ad[2 * e + 1]};
        f32x2 dny = (nyd - nyu) * fy;
        f32x2 L = {(p == 0) ? nlb : nx2[p - 1].y, nx2[p].x};
        f32x2 R = {nx2[p].y, (p == 7) ? nrb : nx2[p + 1].x};
        f32x2 dnx = (R - L) * 0.5f;
        if (p == 0) dnx.x *= exl;
        if (p == 7) dnx.y *= exr;
        f32x2 curv = dnx + dny;
        f32x2 c = ph2[p];
        f32x2 den = c * c + (f32x2){1.f, 1.f};
        f32x2 rcd = {__builtin_amdgcn_rcpf(den.x), __builtin_amdgcn_rcpf(den.y)};
        f32x2 tI = I2[p] * 2.f + (f32x2){ms12, ms12};
        f32x2 force = tI * lam12 + curv;
        f32x2 dphi = (rcd * dtpi) * force;
        f32x2 pn = c + dphi;
        ph2[p] = pn;
        pho[2 * e] = pn.x;
        pho[2 * e + 1] = pn.y;
        f32x2 da = dphi * rcd;
        inc_at2 += da;
        inc_iat2 = I2[p] * da + inc_iat2;
      }
      if (it < 9) *(f32x4*)&phi_l[my + q * 4] = pho;
    }
    if (it < 9) {
      float inc_at = inc_at2.x + inc_at2.y;
      float inc_iat = inc_iat2.x + inc_iat2.y;
#pragma unroll
      for (int off = 32; off; off >>= 1) {
        inc_at += __shfl_xor(inc_at, off);
        inc_iat += __shfl_xor(inc_iat, off);
      }
      if (lane == 0) { red[2 * wv] = inc_at; red[2 * wv + 1] = inc_iat; }
      __syncthreads();
      S_at += red[0] + red[2] + red[4] + red[6];
      S_iat += red[1] + red[3] + red[5] + red[7];
    }
  }

#pragma unroll
  for (int q = 0; q < 4; ++q) {
    f32x2 pa = ph2[2 * q], pb2 = ph2[2 * q + 1];
    float o0 = 1.f / (1.f + exp2f(pa.x * -1.44269504089f));
    float o1 = 1.f / (1.f + exp2f(pa.y * -1.44269504089f));
    float o2 = 1.f / (1.f + exp2f(pb2.x * -1.44269504089f));
    float o3 = 1.f / (1.f + exp2f(pb2.y * -1.44269504089f));
    *(float4*)(ob + gbase + q * 4) = make_float4(o0, o1, o2, o3);
  }
}

extern "C" void kernel_launch(void* const* d_in, const int* in_sizes, int n_in,
                              void* d_out, int out_size, void* d_ws, size_t ws_size,
                              hipStream_t stream)
{
  const float* contour = (const float*)d_in[0];
  const float* g       = (const float*)d_in[1];
  const float* x       = (const float*)d_in[2];
  const float* dt      = (const float*)d_in[3];
  const float* lam     = (const float*)d_in[4];
  const float* g_w     = (const float*)d_in[5];
  const float* x_w     = (const float*)d_in[6];
  const float* c_w     = (const float*)d_in[7];
  float* out = (float*)d_out;
  float* z   = (float*)d_ws;                       // [8,512,64,64] f32 = 64 MiB
  ushort* WH = (ushort*)(z + (size_t)8 * O_CH * PIX);  // +64 MiB
  ushort* WL = WH + W_ELEMS;                       // +1.25 MiB

  conv_w<<<dim3(128, 3), dim3(256), 0, stream>>>(g_w, x_w, c_w, WH, WL);
  mfma_gemm_all<<<dim3(32, 4, 16), dim3(512), 0, stream>>>(
      g, x, contour, WH, WL, z, out);
  chanvese<<<dim3(4096), dim3(256), 0, stream>>>(z, out, dt, lam);
}